// Round 12
// baseline (84.638 us; speedup 1.0000x reference)
//
#include <hip/hip_runtime.h>
#include <hip/hip_bf16.h>

#define NR 1024
#define DV 2048
#define DMM 64
#define DO 2048

typedef __attribute__((ext_vector_type(8))) __bf16 bf16x8;
typedef __attribute__((ext_vector_type(4))) float f32x4;

__device__ __forceinline__ float relu_f(float x) { return fmaxf(x, 0.f); }

__device__ __forceinline__ unsigned short f2bf(float x) {
    union { float f; unsigned int u; } v; v.f = x;
    unsigned int r = v.u + 0x7fffu + ((v.u >> 16) & 1u);   // RNE
    return (unsigned short)(r >> 16);
}

__device__ __forceinline__ float bflo(unsigned int u) {
    union { unsigned int x; float f; } v; v.x = u << 16; return v.f;
}
__device__ __forceinline__ float bfhi(unsigned int u) {
    union { unsigned int x; float f; } v; v.x = u & 0xffff0000u; return v.f;
}

__device__ __forceinline__ void gload_lds16(const void* g, void* l) {
    __builtin_amdgcn_global_load_lds(
        (const __attribute__((address_space(1))) void*)g,
        (__attribute__((address_space(3))) void*)l, 16, 0, 0);
}

// ---------------- prep: convert_fv + 3 weight transposes + box features ----------------
__device__ __forceinline__ void transpose_tile(
    const float* __restrict__ W, unsigned short* __restrict__ Wt,
    int Ncols, int k0, int o0, float (*ld)[65])
{
    const int t = threadIdx.x;
    const int r = t >> 2;
    const int c0 = (t & 3) * 16;
    #pragma unroll
    for (int i = 0; i < 4; ++i) {
        float4 v = *reinterpret_cast<const float4*>(&W[(size_t)(k0 + r) * Ncols + o0 + c0 + i * 4]);
        ld[c0 + i * 4 + 0][r] = v.x;
        ld[c0 + i * 4 + 1][r] = v.y;
        ld[c0 + i * 4 + 2][r] = v.z;
        ld[c0 + i * 4 + 3][r] = v.w;
    }
    __syncthreads();
    const int o = t >> 2;
    const int kc = (t & 3) * 16;
    unsigned int u[8];
    #pragma unroll
    for (int j = 0; j < 8; ++j) {
        float x0 = ld[o][kc + 2 * j], x1 = ld[o][kc + 2 * j + 1];
        u[j] = (unsigned)f2bf(x0) | ((unsigned)f2bf(x1) << 16);
    }
    uint4* dst = reinterpret_cast<uint4*>(&Wt[(size_t)(o0 + o) * DV + k0 + kc]);
    dst[0] = make_uint4(u[0], u[1], u[2], u[3]);
    dst[1] = make_uint4(u[4], u[5], u[6], u[7]);
}

__global__ __launch_bounds__(256) void prep_kernel(
    const float* __restrict__ feat,
    const float* __restrict__ Wk, const float* __restrict__ Wq, const float* __restrict__ Wv,
    const float* __restrict__ rois,
    unsigned short* __restrict__ fvb, unsigned short* __restrict__ WkqT,
    unsigned short* __restrict__ WvT,
    float4* __restrict__ boxf, float2* __restrict__ boxinv)
{
    __shared__ float ld[64][65];
    const int bid = blockIdx.x;
    if (bid < 1024) {
        const int idx = bid * 256 + threadIdx.x;
        const float4 a = *reinterpret_cast<const float4*>(feat + (size_t)idx * 8);
        const float4 b = *reinterpret_cast<const float4*>(feat + (size_t)idx * 8 + 4);
        uint4 o;
        o.x = (unsigned)f2bf(relu_f(a.x)) | ((unsigned)f2bf(relu_f(a.y)) << 16);
        o.y = (unsigned)f2bf(relu_f(a.z)) | ((unsigned)f2bf(relu_f(a.w)) << 16);
        o.z = (unsigned)f2bf(relu_f(b.x)) | ((unsigned)f2bf(relu_f(b.y)) << 16);
        o.w = (unsigned)f2bf(relu_f(b.z)) | ((unsigned)f2bf(relu_f(b.w)) << 16);
        *reinterpret_cast<uint4*>(fvb + (size_t)idx * 8) = o;
    } else if (bid < 2048) {
        const int idx = bid - 1024;                 // 32x32 tiles of Wv
        transpose_tile(Wv, WvT, DO, (idx >> 5) * 64, (idx & 31) * 64, ld);
    } else if (bid < 2080) {
        transpose_tile(Wk, WkqT, DMM, (bid - 2048) * 64, 0, ld);
    } else if (bid < 2112) {
        transpose_tile(Wq, WkqT + 64 * DV, DMM, (bid - 2080) * 64, 0, ld);
    } else {
        const int idx = (bid - 2112) * 256 + threadIdx.x;   // 0..1023
        const float4 r = *reinterpret_cast<const float4*>(rois + (size_t)idx * 4);
        const float w = r.z - r.x, h = r.w - r.y;
        boxf[idx]   = make_float4(0.5f * (r.x + r.z), 0.5f * (r.y + r.w), __logf(w), __logf(h));
        boxinv[idx] = make_float2(1.f / w, 1.f / h);
    }
}

// ---- 64x128 MFMA tile core, BK=64, 2-buffer counted-vmcnt, XOR-swizzled LDS ----
// EXACT Round-9 configuration (64.8 us): the local optimum for this tile shape.
// 256 threads = 4 waves (2x2). Wave tile 32x64; 16 MFMA + 6 gloads per K-step.
// LDS tile: [rows][8 chunks of 16B], row stride 128B. Swizzle (rule #21):
//   slot (row r, c') holds global chunk c' ^ (r&7); stage lane l covers row
//   (g*8 + l>>3) chunk (l&7)^(l>>3) -> 8-lane groups stay 128B-coalesced;
//   read chunk fq^(fr&7) -> banks spread, conflict-free.
// Pipeline: 2 buffers; vmcnt(6) in loop (stage ts done, stage ts+1 in flight);
// vmcnt(0) only in epilogue. Raw s_barrier (no compiler vmcnt-0 drain).
// Do NOT: split the 16-MFMA cluster, setprio, 3-buffer, XCD-swizzle (R10/R11 regressions).
template<int NT, int LDA, int LDB>
__device__ __forceinline__ void mfma_tile_pipe(
    const unsigned short* __restrict__ A, const unsigned short* __restrict__ Bt,
    int bm0, int bn0, unsigned short* As, unsigned short* Bs, f32x4 (&acc)[2][4])
{
    const int t = threadIdx.x;
    const int w = t >> 6, lane = t & 63;
    const int wr = w >> 1, wc = w & 1;
    const int fr = lane & 15, fq = lane >> 4;
    const int sr = lane >> 3;                 // staged row within 8-row group
    const int sc = ((lane & 7) ^ sr) * 8;     // swizzled chunk offset (elements)

    const unsigned short* ga0 = A  + (size_t)(bm0 + w * 16 +  0 + sr) * LDA + sc;
    const unsigned short* ga1 = A  + (size_t)(bm0 + w * 16 +  8 + sr) * LDA + sc;
    const unsigned short* gb0 = Bt + (size_t)(bn0 + w * 32 +  0 + sr) * LDB + sc;
    const unsigned short* gb1 = Bt + (size_t)(bn0 + w * 32 +  8 + sr) * LDB + sc;
    const unsigned short* gb2 = Bt + (size_t)(bn0 + w * 32 + 16 + sr) * LDB + sc;
    const unsigned short* gb3 = Bt + (size_t)(bn0 + w * 32 + 24 + sr) * LDB + sc;

#define STAGE(buf, ts_) do {                                                  \
        const size_t ko_ = (size_t)(ts_) * 64;                                \
        gload_lds16(ga0 + ko_, &As[(buf) * 4096 + w * 1024]);                 \
        gload_lds16(ga1 + ko_, &As[(buf) * 4096 + w * 1024 + 512]);           \
        gload_lds16(gb0 + ko_, &Bs[(buf) * 8192 + w * 2048]);                 \
        gload_lds16(gb1 + ko_, &Bs[(buf) * 8192 + w * 2048 + 512]);           \
        gload_lds16(gb2 + ko_, &Bs[(buf) * 8192 + w * 2048 + 1024]);          \
        gload_lds16(gb3 + ko_, &Bs[(buf) * 8192 + w * 2048 + 1536]);          \
    } while (0)

#define COMPUTE(buf) do {                                                                     \
        const int kx_ = fr & 7;                                                               \
        const int clo_ = (fq ^ kx_) * 8, chi_ = ((fq + 4) ^ kx_) * 8;                         \
        bf16x8 afl[2], afh[2], bfl[4], bfh[4];                                                \
        _Pragma("unroll")                                                                     \
        for (int m = 0; m < 2; ++m) {                                                         \
            const int rb = (buf) * 4096 + (wr * 32 + m * 16 + fr) * 64;                       \
            afl[m] = *reinterpret_cast<const bf16x8*>(&As[rb + clo_]);                        \
            afh[m] = *reinterpret_cast<const bf16x8*>(&As[rb + chi_]);                        \
        }                                                                                     \
        _Pragma("unroll")                                                                     \
        for (int n = 0; n < 4; ++n) {                                                         \
            const int cb = (buf) * 8192 + (wc * 64 + n * 16 + fr) * 64;                       \
            bfl[n] = *reinterpret_cast<const bf16x8*>(&Bs[cb + clo_]);                        \
            bfh[n] = *reinterpret_cast<const bf16x8*>(&Bs[cb + chi_]);                        \
        }                                                                                     \
        _Pragma("unroll")                                                                     \
        for (int m = 0; m < 2; ++m)                                                           \
            _Pragma("unroll")                                                                 \
            for (int n = 0; n < 4; ++n) {                                                     \
                acc[m][n] = __builtin_amdgcn_mfma_f32_16x16x32_bf16(afl[m], bfl[n], acc[m][n], 0, 0, 0); \
                acc[m][n] = __builtin_amdgcn_mfma_f32_16x16x32_bf16(afh[m], bfh[n], acc[m][n], 0, 0, 0); \
            }                                                                                 \
    } while (0)

    STAGE(0, 0);
    if (NT > 1) STAGE(1, 1);

    #pragma unroll 2
    for (int ts = 0; ts < NT - 1; ++ts) {
        asm volatile("s_waitcnt vmcnt(6)" ::: "memory");   // own stage ts done
        asm volatile("s_barrier" ::: "memory");            // all waves' stage ts done
        COMPUTE(ts & 1);
        asm volatile("s_barrier" ::: "memory");            // all waves done reading buf
        if (ts + 2 < NT) STAGE(ts & 1, ts + 2);
    }
    asm volatile("s_waitcnt vmcnt(0)" ::: "memory");
    asm volatile("s_barrier" ::: "memory");
    COMPUTE((NT - 1) & 1);
#undef STAGE
#undef COMPUTE
}

// ---------------- fused vT GEMM (256 blocks) + kq GEMM (16 blocks) ----------------
// vT[DO][NR] = WvT[DO][DV] @ fvb[NR][DV]^T + bv[row]          (bf16 out)
// kqb[NR][128] = fvb[NR][DV] @ WkqT[128][DV]^T + {bk|bq}[col]  (bf16 out)
// Default bid->XCD round-robin keeps bn0 constant per XCD: do NOT swizzle (R10).
__global__ __launch_bounds__(256) void gemm_vt_kq(
    const unsigned short* __restrict__ WvT, const unsigned short* __restrict__ fvb,
    const unsigned short* __restrict__ WkqT,
    const float* __restrict__ bv, const float* __restrict__ bk, const float* __restrict__ bq,
    unsigned short* __restrict__ vT, unsigned short* __restrict__ kqb)
{
    __shared__ unsigned short As[2 * 64 * 64];    // 16 KB
    __shared__ unsigned short Bs[2 * 128 * 64];   // 32 KB
    const int bid = blockIdx.x;
    const bool is_kq = bid >= 256;
    const unsigned short* A  = is_kq ? fvb  : WvT;
    const unsigned short* Bt = is_kq ? WkqT : fvb;
    const int bm0 = is_kq ? (bid - 256) * 64 : (bid >> 3) * 64;
    const int bn0 = is_kq ? 0 : (bid & 7) * 128;

    f32x4 acc[2][4] = {};
    mfma_tile_pipe<DV / 64, DV, DV>(A, Bt, bm0, bn0, As, Bs, acc);

    const int t = threadIdx.x;
    const int w = t >> 6, lane = t & 63;
    const int wr = w >> 1, wc = w & 1;
    const int fr = lane & 15, fq = lane >> 4;
    if (!is_kq) {
        #pragma unroll
        for (int m = 0; m < 2; ++m)
            #pragma unroll
            for (int r = 0; r < 4; ++r) {
                const int row = bm0 + wr * 32 + m * 16 + fq * 4 + r;
                const float badd = bv[row];
                #pragma unroll
                for (int n = 0; n < 4; ++n) {
                    const int col = bn0 + wc * 64 + n * 16 + fr;
                    vT[(size_t)row * NR + col] = f2bf(acc[m][n][r] + badd);
                }
            }
    } else {
        #pragma unroll
        for (int m = 0; m < 2; ++m)
            #pragma unroll
            for (int r = 0; r < 4; ++r) {
                const int row = bm0 + wr * 32 + m * 16 + fq * 4 + r;
                #pragma unroll
                for (int n = 0; n < 4; ++n) {
                    const int col = wc * 64 + n * 16 + fr;
                    const float badd = (col < 64) ? bk[col] : bq[col - 64];
                    kqb[(size_t)row * 128 + col] = f2bf(acc[m][n][r] + badd);
                }
            }
    }
}

// ---------------- out GEMM: out[NR][DO] = attb[NR][NR] @ vT[DO][NR]^T (256 blocks) ----------------
__global__ __launch_bounds__(256) void gemm_out(
    const unsigned short* __restrict__ attb, const unsigned short* __restrict__ vT,
    float* __restrict__ out)
{
    __shared__ unsigned short As[2 * 64 * 64];
    __shared__ unsigned short Bs[2 * 128 * 64];
    const int bm0 = blockIdx.y * 64;
    const int bn0 = blockIdx.x * 128;
    f32x4 acc[2][4] = {};
    mfma_tile_pipe<NR / 64, NR, NR>(attb, vT, bm0, bn0, As, Bs, acc);
    const int t = threadIdx.x;
    const int w = t >> 6, lane = t & 63;
    const int wr = w >> 1, wc = w & 1;
    const int fr = lane & 15, fq = lane >> 4;
    #pragma unroll
    for (int m = 0; m < 2; ++m)
        #pragma unroll
        for (int r = 0; r < 4; ++r) {
            const int row = bm0 + wr * 32 + m * 16 + fq * 4 + r;
            #pragma unroll
            for (int n = 0; n < 4; ++n) {
                const int col = bn0 + wc * 64 + n * 16 + fr;
                out[(size_t)row * DO + col] = acc[m][n][r];
            }
        }
}

// ---------------- attention row kernel: fused score dot + geometry MLP ----------------
// Block i (1024 blocks x 256 threads); thread handles j = ch*256 + t, ch=0..3.
// Score: dot(k_i, q_j)/8 computed inline from L2-hot kqb (no S matrix, no gemm_s).
// k_i unpacked once to LDS f32; q_j read as uint4 + shift-unpack.
#define MLP_STEP(A_, B_, C_, D_, E_, F_)                                            \
    {                                                                               \
        float h_ = fmaf(ff1[ch], A_, fmaf(ff2[ch], B_, fmaf(ff3[ch], C_,            \
                   fmaf(ff4[ch], D_, E_))));                                        \
        h_ = fmaxf(h_, 0.f);                                                        \
        gw[ch] = fmaf(h_, F_, gw[ch]);                                              \
    }

__global__ __launch_bounds__(256) void attn_kernel(
    const unsigned short* __restrict__ kqb,
    const float4* __restrict__ boxf, const float2* __restrict__ boxinv,
    const float* __restrict__ G1, const float* __restrict__ g1,
    const float* __restrict__ G2, const float* __restrict__ g2,
    unsigned short* __restrict__ att)
{
    __shared__ float G1s[4][64];
    __shared__ float g1s[64];
    __shared__ float G2s[64];
    __shared__ float ksf[64];
    __shared__ float red[4];
    const int i = blockIdx.x;
    const int t = threadIdx.x;
    if (t < 64) {
        G1s[0][t] = G1[t];
        G1s[1][t] = G1[64 + t];
        G1s[2][t] = G1[128 + t];
        G1s[3][t] = G1[192 + t];
        g1s[t] = g1[t];
        G2s[t] = G2[t];
        ksf[t] = bflo((unsigned int)kqb[(size_t)i * 128 + t]);   // k_i[t] -> f32
    }
    __syncthreads();
    const float4 bi = boxf[i];
    const float2 ivi = boxinv[i];
    const float g2v = g2[0];

    // ---- score dot: sc[ch] = <k_i, q_j> / 8 ----
    float dot[4] = {0.f, 0.f, 0.f, 0.f};
    #pragma unroll
    for (int c4 = 0; c4 < 8; ++c4) {
        const float4 k0 = *reinterpret_cast<const float4*>(&ksf[c4 * 8]);
        const float4 k1 = *reinterpret_cast<const float4*>(&ksf[c4 * 8 + 4]);
        #pragma unroll
        for (int ch = 0; ch < 4; ++ch) {
            const int j = ch * 256 + t;
            const uint4 qv = *reinterpret_cast<const uint4*>(
                &kqb[(size_t)j * 128 + 64 + c4 * 8]);
            float d = dot[ch];
            d = fmaf(k0.x, bflo(qv.x), d); d = fmaf(k0.y, bfhi(qv.x), d);
            d = fmaf(k0.z, bflo(qv.y), d); d = fmaf(k0.w, bfhi(qv.y), d);
            d = fmaf(k1.x, bflo(qv.z), d); d = fmaf(k1.y, bfhi(qv.z), d);
            d = fmaf(k1.z, bflo(qv.w), d); d = fmaf(k1.w, bfhi(qv.w), d);
            dot[ch] = d;
        }
    }

    float ff1[4], ff2[4], ff3[4], ff4[4], sc[4], gw[4] = {0.f, 0.f, 0.f, 0.f};
    #pragma unroll
    for (int ch = 0; ch < 4; ++ch) {
        const int j = ch * 256 + t;
        const float4 bj = boxf[j];
        sc[ch] = dot[ch] * 0.125f;
        ff1[ch] = __logf(fmaf(fabsf(bj.x - bi.x), ivi.x, 1e-3f));
        ff2[ch] = __logf(fmaf(fabsf(bj.y - bi.y), ivi.y, 1e-3f));
        ff3[ch] = bj.z - bi.z;
        ff4[ch] = bj.w - bi.w;
    }

    for (int mt = 0; mt < 64; mt += 8) {
        const float4 A0 = *reinterpret_cast<const float4*>(&G1s[0][mt]);
        const float4 A1 = *reinterpret_cast<const float4*>(&G1s[0][mt + 4]);
        const float4 B0 = *reinterpret_cast<const float4*>(&G1s[1][mt]);
        const float4 B1 = *reinterpret_cast<const float4*>(&G1s[1][mt + 4]);
        const float4 C0 = *reinterpret_cast<const float4*>(&G1s[2][mt]);
        const float4 C1 = *reinterpret_cast<const float4*>(&G1s[2][mt + 4]);
        const float4 D0 = *reinterpret_cast<const float4*>(&G1s[3][mt]);
        const float4 D1 = *reinterpret_cast<const float4*>(&G1s[3][mt + 4]);
        const float4 E0 = *reinterpret_cast<const float4*>(&g1s[mt]);
        const float4 E1 = *reinterpret_cast<const float4*>(&g1s[mt + 4]);
        const float4 F0 = *reinterpret_cast<const float4*>(&G2s[mt]);
        const float4 F1 = *reinterpret_cast<const float4*>(&G2s[mt + 4]);
        #pragma unroll
        for (int ch = 0; ch < 4; ++ch) {
            MLP_STEP(A0.x, B0.x, C0.x, D0.x, E0.x, F0.x)
            MLP_STEP(A0.y, B0.y, C0.y, D0.y, E0.y, F0.y)
            MLP_STEP(A0.z, B0.z, C0.z, D0.z, E0.z, F0.z)
            MLP_STEP(A0.w, B0.w, C0.w, D0.w, E0.w, F0.w)
            MLP_STEP(A1.x, B1.x, C1.x, D1.x, E1.x, F1.x)
            MLP_STEP(A1.y, B1.y, C1.y, D1.y, E1.y, F1.y)
            MLP_STEP(A1.z, B1.z, C1.z, D1.z, E1.z, F1.z)
            MLP_STEP(A1.w, B1.w, C1.w, D1.w, E1.w, F1.w)
        }
    }

    float vals[4];
    float rsum = 0.f;
    #pragma unroll
    for (int ch = 0; ch < 4; ++ch) {
        const float gwp = fmaxf(gw[ch] + g2v, 0.f);
        float a = __expf(sc[ch]) * gwp;
        if (ch * 256 + t == i) a = 0.f;
        vals[ch] = a;
        rsum += a;
    }
    #pragma unroll
    for (int o = 32; o > 0; o >>= 1) rsum += __shfl_down(rsum, o, 64);
    if ((t & 63) == 0) red[t >> 6] = rsum;
    __syncthreads();
    const float inv = 1.f / (red[0] + red[1] + red[2] + red[3] + 1e-10f);
    #pragma unroll
    for (int ch = 0; ch < 4; ++ch)
        att[(size_t)i * NR + ch * 256 + t] = f2bf(vals[ch] * inv);
}

extern "C" void kernel_launch(void* const* d_in, const int* in_sizes, int n_in,
                              void* d_out, int out_size, void* d_ws, size_t ws_size,
                              hipStream_t stream) {
    const float* feat = (const float*)d_in[0];
    const float* rois = (const float*)d_in[1];
    const float* Wk   = (const float*)d_in[2];
    const float* bk   = (const float*)d_in[3];
    const float* Wq   = (const float*)d_in[4];
    const float* bq   = (const float*)d_in[5];
    const float* Wv   = (const float*)d_in[6];
    const float* bv   = (const float*)d_in[7];
    const float* G1   = (const float*)d_in[8];
    const float* g1   = (const float*)d_in[9];
    const float* G2   = (const float*)d_in[10];
    const float* g2   = (const float*)d_in[11];
    float* out = (float*)d_out;
    char* ws = (char*)d_ws;

    unsigned short* kqb  = (unsigned short*)ws;                                  // 256 KB
    float4* boxf         = (float4*)(ws + (256 << 10));                          // 16 KB
    float2* boxinv       = (float2*)(ws + (272 << 10));                          // 8 KB
    unsigned short* fvb  = (unsigned short*)(ws + (512 << 10));                  // 4 MB
    unsigned short* WvT  = (unsigned short*)(ws + (512 << 10) + (4 << 20));      // 8 MB
    unsigned short* WkqT = (unsigned short*)(ws + (512 << 10) + (12 << 20));     // 512 KB
    unsigned short* vT   = (unsigned short*)(ws + (1024 << 10) + (12 << 20));    // 4 MB
    unsigned short* attb = (unsigned short*)(ws + (1024 << 10) + (16 << 20));    // 2 MB

    prep_kernel<<<2116, 256, 0, stream>>>(feat, Wk, Wq, Wv, rois, fvb, WkqT, WvT, boxf, boxinv);
    gemm_vt_kq<<<272, 256, 0, stream>>>(WvT, fvb, WkqT, bv, bk, bq, vT, kqb);
    attn_kernel<<<NR, 256, 0, stream>>>(kqb, boxf, boxinv, G1, g1, G2, g2, attb);
    gemm_out<<<dim3(DO / 128, NR / 64), 256, 0, stream>>>(attb, vT, out);
}

// Round 13
// 73.594 us; speedup vs baseline: 1.1501x; 1.1501x over previous
//
#include <hip/hip_runtime.h>
#include <hip/hip_bf16.h>

#define NR 1024
#define DV 2048
#define DMM 64
#define DO 2048

typedef __attribute__((ext_vector_type(8))) __bf16 bf16x8;
typedef __attribute__((ext_vector_type(4))) float f32x4;

__device__ __forceinline__ float relu_f(float x) { return fmaxf(x, 0.f); }

__device__ __forceinline__ unsigned short f2bf(float x) {
    union { float f; unsigned int u; } v; v.f = x;
    unsigned int r = v.u + 0x7fffu + ((v.u >> 16) & 1u);   // RNE
    return (unsigned short)(r >> 16);
}

__device__ __forceinline__ void gload_lds16(const void* g, void* l) {
    __builtin_amdgcn_global_load_lds(
        (const __attribute__((address_space(1))) void*)g,
        (__attribute__((address_space(3))) void*)l, 16, 0, 0);
}

// ---------------- prep: convert_fv + 3 weight transposes + box features ----------------
__device__ __forceinline__ void transpose_tile(
    const float* __restrict__ W, unsigned short* __restrict__ Wt,
    int Ncols, int k0, int o0, float (*ld)[65])
{
    const int t = threadIdx.x;
    const int r = t >> 2;
    const int c0 = (t & 3) * 16;
    #pragma unroll
    for (int i = 0; i < 4; ++i) {
        float4 v = *reinterpret_cast<const float4*>(&W[(size_t)(k0 + r) * Ncols + o0 + c0 + i * 4]);
        ld[c0 + i * 4 + 0][r] = v.x;
        ld[c0 + i * 4 + 1][r] = v.y;
        ld[c0 + i * 4 + 2][r] = v.z;
        ld[c0 + i * 4 + 3][r] = v.w;
    }
    __syncthreads();
    const int o = t >> 2;
    const int kc = (t & 3) * 16;
    unsigned int u[8];
    #pragma unroll
    for (int j = 0; j < 8; ++j) {
        float x0 = ld[o][kc + 2 * j], x1 = ld[o][kc + 2 * j + 1];
        u[j] = (unsigned)f2bf(x0) | ((unsigned)f2bf(x1) << 16);
    }
    uint4* dst = reinterpret_cast<uint4*>(&Wt[(size_t)(o0 + o) * DV + k0 + kc]);
    dst[0] = make_uint4(u[0], u[1], u[2], u[3]);
    dst[1] = make_uint4(u[4], u[5], u[6], u[7]);
}

__global__ __launch_bounds__(256) void prep_kernel(
    const float* __restrict__ feat,
    const float* __restrict__ Wk, const float* __restrict__ Wq, const float* __restrict__ Wv,
    const float* __restrict__ rois,
    unsigned short* __restrict__ fvb, unsigned short* __restrict__ WkqT,
    unsigned short* __restrict__ WvT,
    float4* __restrict__ boxf, float2* __restrict__ boxinv)
{
    __shared__ float ld[64][65];
    const int bid = blockIdx.x;
    if (bid < 1024) {
        const int idx = bid * 256 + threadIdx.x;
        const float4 a = *reinterpret_cast<const float4*>(feat + (size_t)idx * 8);
        const float4 b = *reinterpret_cast<const float4*>(feat + (size_t)idx * 8 + 4);
        uint4 o;
        o.x = (unsigned)f2bf(relu_f(a.x)) | ((unsigned)f2bf(relu_f(a.y)) << 16);
        o.y = (unsigned)f2bf(relu_f(a.z)) | ((unsigned)f2bf(relu_f(a.w)) << 16);
        o.z = (unsigned)f2bf(relu_f(b.x)) | ((unsigned)f2bf(relu_f(b.y)) << 16);
        o.w = (unsigned)f2bf(relu_f(b.z)) | ((unsigned)f2bf(relu_f(b.w)) << 16);
        *reinterpret_cast<uint4*>(fvb + (size_t)idx * 8) = o;
    } else if (bid < 2048) {
        const int idx = bid - 1024;                 // 32x32 tiles of Wv
        transpose_tile(Wv, WvT, DO, (idx >> 5) * 64, (idx & 31) * 64, ld);
    } else if (bid < 2080) {
        transpose_tile(Wk, WkqT, DMM, (bid - 2048) * 64, 0, ld);
    } else if (bid < 2112) {
        transpose_tile(Wq, WkqT + 64 * DV, DMM, (bid - 2080) * 64, 0, ld);
    } else {
        const int idx = (bid - 2112) * 256 + threadIdx.x;   // 0..1023
        const float4 r = *reinterpret_cast<const float4*>(rois + (size_t)idx * 4);
        const float w = r.z - r.x, h = r.w - r.y;
        boxf[idx]   = make_float4(0.5f * (r.x + r.z), 0.5f * (r.y + r.w), __logf(w), __logf(h));
        boxinv[idx] = make_float2(1.f / w, 1.f / h);
    }
}

// ---- 64x128 MFMA tile core, BK=64, XOR-swizzled LDS (R9 layout/compute) ----
// SINGLE CHANGE vs R9 (64.8us): 3 buffers, STAGE(ts+2) issued right after
// barrier#1 (before the fused 16-MFMA COMPUTE) -> each stage gets ~2 compute
// phases of flight instead of ~1. Fused COMPUTE, no setprio, default block
// mapping (isolating R10's pipeline from its bad XCD swizzle).
// Swizzle (rule #21): slot (row r, c') holds global chunk c'^(r&7); stage lane
// l covers row (g*8 + l>>3) chunk (l&7)^(l>>3) (128B-coalesced); read chunk
// fq^(fr&7) -> conflict-free. vmcnt(6) in loop; vmcnt(0) only in epilogue.
template<int NT, int LDA, int LDB>
__device__ __forceinline__ void mfma_tile_pipe(
    const unsigned short* __restrict__ A, const unsigned short* __restrict__ Bt,
    int bm0, int bn0, unsigned short* As, unsigned short* Bs, f32x4 (&acc)[2][4])
{
    const int t = threadIdx.x;
    const int w = t >> 6, lane = t & 63;
    const int wr = w >> 1, wc = w & 1;
    const int fr = lane & 15, fq = lane >> 4;
    const int sr = lane >> 3;                 // staged row within 8-row group
    const int sc = ((lane & 7) ^ sr) * 8;     // swizzled chunk offset (elements)

    const unsigned short* ga0 = A  + (size_t)(bm0 + w * 16 +  0 + sr) * LDA + sc;
    const unsigned short* ga1 = A  + (size_t)(bm0 + w * 16 +  8 + sr) * LDA + sc;
    const unsigned short* gb0 = Bt + (size_t)(bn0 + w * 32 +  0 + sr) * LDB + sc;
    const unsigned short* gb1 = Bt + (size_t)(bn0 + w * 32 +  8 + sr) * LDB + sc;
    const unsigned short* gb2 = Bt + (size_t)(bn0 + w * 32 + 16 + sr) * LDB + sc;
    const unsigned short* gb3 = Bt + (size_t)(bn0 + w * 32 + 24 + sr) * LDB + sc;

#define STAGE(buf, ts_) do {                                                  \
        const size_t ko_ = (size_t)(ts_) * 64;                                \
        gload_lds16(ga0 + ko_, &As[(buf) * 4096 + w * 1024]);                 \
        gload_lds16(ga1 + ko_, &As[(buf) * 4096 + w * 1024 + 512]);           \
        gload_lds16(gb0 + ko_, &Bs[(buf) * 8192 + w * 2048]);                 \
        gload_lds16(gb1 + ko_, &Bs[(buf) * 8192 + w * 2048 + 512]);           \
        gload_lds16(gb2 + ko_, &Bs[(buf) * 8192 + w * 2048 + 1024]);          \
        gload_lds16(gb3 + ko_, &Bs[(buf) * 8192 + w * 2048 + 1536]);          \
    } while (0)

#define COMPUTE(buf) do {                                                                     \
        const int kx_ = fr & 7;                                                               \
        const int clo_ = (fq ^ kx_) * 8, chi_ = ((fq + 4) ^ kx_) * 8;                         \
        bf16x8 afl[2], afh[2], bfl[4], bfh[4];                                                \
        _Pragma("unroll")                                                                     \
        for (int m = 0; m < 2; ++m) {                                                         \
            const int rb = (buf) * 4096 + (wr * 32 + m * 16 + fr) * 64;                       \
            afl[m] = *reinterpret_cast<const bf16x8*>(&As[rb + clo_]);                        \
            afh[m] = *reinterpret_cast<const bf16x8*>(&As[rb + chi_]);                        \
        }                                                                                     \
        _Pragma("unroll")                                                                     \
        for (int n = 0; n < 4; ++n) {                                                         \
            const int cb = (buf) * 8192 + (wc * 64 + n * 16 + fr) * 64;                       \
            bfl[n] = *reinterpret_cast<const bf16x8*>(&Bs[cb + clo_]);                        \
            bfh[n] = *reinterpret_cast<const bf16x8*>(&Bs[cb + chi_]);                        \
        }                                                                                     \
        _Pragma("unroll")                                                                     \
        for (int m = 0; m < 2; ++m)                                                           \
            _Pragma("unroll")                                                                 \
            for (int n = 0; n < 4; ++n) {                                                     \
                acc[m][n] = __builtin_amdgcn_mfma_f32_16x16x32_bf16(afl[m], bfl[n], acc[m][n], 0, 0, 0); \
                acc[m][n] = __builtin_amdgcn_mfma_f32_16x16x32_bf16(afh[m], bfh[n], acc[m][n], 0, 0, 0); \
            }                                                                                 \
    } while (0)

    STAGE(0, 0);
    if (NT > 1) STAGE(1, 1);

    #pragma unroll 3
    for (int ts = 0; ts < NT - 1; ++ts) {
        asm volatile("s_waitcnt vmcnt(6)" ::: "memory");   // own stage ts done
        asm volatile("s_barrier" ::: "memory");            // all waves' stage ts done
        if (ts + 2 < NT) STAGE((ts + 2) % 3, ts + 2);      // early issue: ~2 phases to fly
        COMPUTE(ts % 3);
        asm volatile("s_barrier" ::: "memory");            // all waves done reading buf
    }
    asm volatile("s_waitcnt vmcnt(0)" ::: "memory");
    asm volatile("s_barrier" ::: "memory");
    COMPUTE((NT - 1) % 3);
#undef STAGE
#undef COMPUTE
}

// ---------------- fused vT GEMM (256 blocks) + kq GEMM (16 blocks) ----------------
// vT[DO][NR] = WvT[DO][DV] @ fvb[NR][DV]^T + bv[row]          (bf16 out)
// kqb[NR][128] = fvb[NR][DV] @ WkqT[128][DV]^T + {bk|bq}[col]  (bf16 out)
// Default bid->XCD round-robin keeps bn0 constant per XCD: do NOT swizzle (R10).
__global__ __launch_bounds__(256) void gemm_vt_kq(
    const unsigned short* __restrict__ WvT, const unsigned short* __restrict__ fvb,
    const unsigned short* __restrict__ WkqT,
    const float* __restrict__ bv, const float* __restrict__ bk, const float* __restrict__ bq,
    unsigned short* __restrict__ vT, unsigned short* __restrict__ kqb)
{
    __shared__ unsigned short As[3 * 64 * 64];    // 24 KB
    __shared__ unsigned short Bs[3 * 128 * 64];   // 48 KB
    const int bid = blockIdx.x;
    const bool is_kq = bid >= 256;
    const unsigned short* A  = is_kq ? fvb  : WvT;
    const unsigned short* Bt = is_kq ? WkqT : fvb;
    const int bm0 = is_kq ? (bid - 256) * 64 : (bid >> 3) * 64;
    const int bn0 = is_kq ? 0 : (bid & 7) * 128;

    f32x4 acc[2][4] = {};
    mfma_tile_pipe<DV / 64, DV, DV>(A, Bt, bm0, bn0, As, Bs, acc);

    const int t = threadIdx.x;
    const int w = t >> 6, lane = t & 63;
    const int wr = w >> 1, wc = w & 1;
    const int fr = lane & 15, fq = lane >> 4;
    if (!is_kq) {
        #pragma unroll
        for (int m = 0; m < 2; ++m)
            #pragma unroll
            for (int r = 0; r < 4; ++r) {
                const int row = bm0 + wr * 32 + m * 16 + fq * 4 + r;
                const float badd = bv[row];
                #pragma unroll
                for (int n = 0; n < 4; ++n) {
                    const int col = bn0 + wc * 64 + n * 16 + fr;
                    vT[(size_t)row * NR + col] = f2bf(acc[m][n][r] + badd);
                }
            }
    } else {
        #pragma unroll
        for (int m = 0; m < 2; ++m)
            #pragma unroll
            for (int r = 0; r < 4; ++r) {
                const int row = bm0 + wr * 32 + m * 16 + fq * 4 + r;
                #pragma unroll
                for (int n = 0; n < 4; ++n) {
                    const int col = wc * 64 + n * 16 + fr;
                    const float badd = (col < 64) ? bk[col] : bq[col - 64];
                    kqb[(size_t)row * 128 + col] = f2bf(acc[m][n][r] + badd);
                }
            }
    }
}

// ---------------- S[i][j] = 0.125 * <k_i, q_j>  (K=64 MFMA GEMM, 128 blocks) ----------------
__global__ __launch_bounds__(256) void gemm_s(
    const unsigned short* __restrict__ kqb, float* __restrict__ S)
{
    __shared__ unsigned short As[64 * 64];     // NT=1: only buffer 0 used
    __shared__ unsigned short Bs[128 * 64];
    const int bm0 = blockIdx.y * 64;
    const int bn0 = blockIdx.x * 128;
    f32x4 acc[2][4] = {};
    mfma_tile_pipe<1, 128, 128>(kqb, kqb + 64, bm0, bn0, As, Bs, acc);
    const int t = threadIdx.x;
    const int w = t >> 6, lane = t & 63;
    const int wr = w >> 1, wc = w & 1;
    const int fr = lane & 15, fq = lane >> 4;
    #pragma unroll
    for (int m = 0; m < 2; ++m)
        #pragma unroll
        for (int r = 0; r < 4; ++r) {
            const int row = bm0 + wr * 32 + m * 16 + fq * 4 + r;
            #pragma unroll
            for (int n = 0; n < 4; ++n) {
                const int col = bn0 + wc * 64 + n * 16 + fr;
                S[(size_t)row * NR + col] = acc[m][n][r] * 0.125f;
            }
        }
}

// ---------------- out GEMM: out[NR][DO] = attb[NR][NR] @ vT[DO][NR]^T (256 blocks) ----------------
__global__ __launch_bounds__(256) void gemm_out(
    const unsigned short* __restrict__ attb, const unsigned short* __restrict__ vT,
    float* __restrict__ out)
{
    __shared__ unsigned short As[3 * 64 * 64];
    __shared__ unsigned short Bs[3 * 128 * 64];
    const int bm0 = blockIdx.y * 64;
    const int bn0 = blockIdx.x * 128;
    f32x4 acc[2][4] = {};
    mfma_tile_pipe<NR / 64, NR, NR>(attb, vT, bm0, bn0, As, Bs, acc);
    const int t = threadIdx.x;
    const int w = t >> 6, lane = t & 63;
    const int wr = w >> 1, wc = w & 1;
    const int fr = lane & 15, fq = lane >> 4;
    #pragma unroll
    for (int m = 0; m < 2; ++m)
        #pragma unroll
        for (int r = 0; r < 4; ++r) {
            const int row = bm0 + wr * 32 + m * 16 + fq * 4 + r;
            #pragma unroll
            for (int n = 0; n < 4; ++n) {
                const int col = bn0 + wc * 64 + n * 16 + fr;
                out[(size_t)row * DO + col] = acc[m][n][r];
            }
        }
}

// ---------------- attention row kernel: VALU-only MLP, S precomputed (R9 version) ----------------
#define MLP_STEP(A_, B_, C_, D_, E_, F_)                                            \
    {                                                                               \
        float h_ = fmaf(ff1[ch], A_, fmaf(ff2[ch], B_, fmaf(ff3[ch], C_,            \
                   fmaf(ff4[ch], D_, E_))));                                        \
        h_ = fmaxf(h_, 0.f);                                                        \
        gw[ch] = fmaf(h_, F_, gw[ch]);                                              \
    }

__global__ __launch_bounds__(256) void attn_kernel(
    const float* __restrict__ S,
    const float4* __restrict__ boxf, const float2* __restrict__ boxinv,
    const float* __restrict__ G1, const float* __restrict__ g1,
    const float* __restrict__ G2, const float* __restrict__ g2,
    unsigned short* __restrict__ att)
{
    __shared__ float G1s[4][64];
    __shared__ float g1s[64];
    __shared__ float G2s[64];
    __shared__ float red[4];
    const int i = blockIdx.x;
    const int t = threadIdx.x;
    if (t < 64) {
        G1s[0][t] = G1[t];
        G1s[1][t] = G1[64 + t];
        G1s[2][t] = G1[128 + t];
        G1s[3][t] = G1[192 + t];
        g1s[t] = g1[t];
        G2s[t] = G2[t];
    }
    __syncthreads();
    const float4 bi = boxf[i];
    const float2 ivi = boxinv[i];
    const float g2v = g2[0];

    float ff1[4], ff2[4], ff3[4], ff4[4], sc[4], gw[4] = {0.f, 0.f, 0.f, 0.f};
    #pragma unroll
    for (int ch = 0; ch < 4; ++ch) {
        const int j = ch * 256 + t;
        const float4 bj = boxf[j];
        sc[ch] = S[(size_t)i * NR + j];
        ff1[ch] = __logf(fmaf(fabsf(bj.x - bi.x), ivi.x, 1e-3f));
        ff2[ch] = __logf(fmaf(fabsf(bj.y - bi.y), ivi.y, 1e-3f));
        ff3[ch] = bj.z - bi.z;
        ff4[ch] = bj.w - bi.w;
    }

    for (int mt = 0; mt < 64; mt += 8) {
        const float4 A0 = *reinterpret_cast<const float4*>(&G1s[0][mt]);
        const float4 A1 = *reinterpret_cast<const float4*>(&G1s[0][mt + 4]);
        const float4 B0 = *reinterpret_cast<const float4*>(&G1s[1][mt]);
        const float4 B1 = *reinterpret_cast<const float4*>(&G1s[1][mt + 4]);
        const float4 C0 = *reinterpret_cast<const float4*>(&G1s[2][mt]);
        const float4 C1 = *reinterpret_cast<const float4*>(&G1s[2][mt + 4]);
        const float4 D0 = *reinterpret_cast<const float4*>(&G1s[3][mt]);
        const float4 D1 = *reinterpret_cast<const float4*>(&G1s[3][mt + 4]);
        const float4 E0 = *reinterpret_cast<const float4*>(&g1s[mt]);
        const float4 E1 = *reinterpret_cast<const float4*>(&g1s[mt + 4]);
        const float4 F0 = *reinterpret_cast<const float4*>(&G2s[mt]);
        const float4 F1 = *reinterpret_cast<const float4*>(&G2s[mt + 4]);
        #pragma unroll
        for (int ch = 0; ch < 4; ++ch) {
            MLP_STEP(A0.x, B0.x, C0.x, D0.x, E0.x, F0.x)
            MLP_STEP(A0.y, B0.y, C0.y, D0.y, E0.y, F0.y)
            MLP_STEP(A0.z, B0.z, C0.z, D0.z, E0.z, F0.z)
            MLP_STEP(A0.w, B0.w, C0.w, D0.w, E0.w, F0.w)
            MLP_STEP(A1.x, B1.x, C1.x, D1.x, E1.x, F1.x)
            MLP_STEP(A1.y, B1.y, C1.y, D1.y, E1.y, F1.y)
            MLP_STEP(A1.z, B1.z, C1.z, D1.z, E1.z, F1.z)
            MLP_STEP(A1.w, B1.w, C1.w, D1.w, E1.w, F1.w)
        }
    }

    float vals[4];
    float rsum = 0.f;
    #pragma unroll
    for (int ch = 0; ch < 4; ++ch) {
        const float gwp = fmaxf(gw[ch] + g2v, 0.f);
        float a = __expf(sc[ch]) * gwp;
        if (ch * 256 + t == i) a = 0.f;
        vals[ch] = a;
        rsum += a;
    }
    #pragma unroll
    for (int o = 32; o > 0; o >>= 1) rsum += __shfl_down(rsum, o, 64);
    if ((t & 63) == 0) red[t >> 6] = rsum;
    __syncthreads();
    const float inv = 1.f / (red[0] + red[1] + red[2] + red[3] + 1e-10f);
    #pragma unroll
    for (int ch = 0; ch < 4; ++ch)
        att[(size_t)i * NR + ch * 256 + t] = f2bf(vals[ch] * inv);
}

extern "C" void kernel_launch(void* const* d_in, const int* in_sizes, int n_in,
                              void* d_out, int out_size, void* d_ws, size_t ws_size,
                              hipStream_t stream) {
    const float* feat = (const float*)d_in[0];
    const float* rois = (const float*)d_in[1];
    const float* Wk   = (const float*)d_in[2];
    const float* bk   = (const float*)d_in[3];
    const float* Wq   = (const float*)d_in[4];
    const float* bq   = (const float*)d_in[5];
    const float* Wv   = (const float*)d_in[6];
    const float* bv   = (const float*)d_in[7];
    const float* G1   = (const float*)d_in[8];
    const float* g1   = (const float*)d_in[9];
    const float* G2   = (const float*)d_in[10];
    const float* g2   = (const float*)d_in[11];
    float* out = (float*)d_out;
    char* ws = (char*)d_ws;

    unsigned short* kqb  = (unsigned short*)ws;                                  // 256 KB
    float4* boxf         = (float4*)(ws + (256 << 10));                          // 16 KB
    float2* boxinv       = (float2*)(ws + (272 << 10));                          // 8 KB
    unsigned short* fvb  = (unsigned short*)(ws + (512 << 10));                  // 4 MB
    unsigned short* WvT  = (unsigned short*)(ws + (512 << 10) + (4 << 20));      // 8 MB
    unsigned short* WkqT = (unsigned short*)(ws + (512 << 10) + (12 << 20));     // 512 KB
    unsigned short* vT   = (unsigned short*)(ws + (1024 << 10) + (12 << 20));    // 4 MB
    unsigned short* attb = (unsigned short*)(ws + (1024 << 10) + (16 << 20));    // 2 MB
    float* Sbuf          = (float*)(ws + (1024 << 10) + (18 << 20));             // 4 MB

    prep_kernel<<<2116, 256, 0, stream>>>(feat, Wk, Wq, Wv, rois, fvb, WkqT, WvT, boxf, boxinv);
    gemm_vt_kq<<<272, 256, 0, stream>>>(WvT, fvb, WkqT, bv, bk, bq, vT, kqb);
    gemm_s<<<dim3(8, 16), 256, 0, stream>>>(kqb, Sbuf);
    attn_kernel<<<NR, 256, 0, stream>>>(Sbuf, boxf, boxinv, G1, g1, G2, g2, attb);
    gemm_out<<<dim3(DO / 128, NR / 64), 256, 0, stream>>>(attb, vT, out);
}

// Round 14
// 68.218 us; speedup vs baseline: 1.2407x; 1.0788x over previous
//
#include <hip/hip_runtime.h>
#include <hip/hip_bf16.h>

#define NR 1024
#define DV 2048
#define DMM 64
#define DO 2048

typedef __attribute__((ext_vector_type(8))) __bf16 bf16x8;
typedef __attribute__((ext_vector_type(8))) unsigned short u16x8;
typedef __attribute__((ext_vector_type(4))) float f32x4;

__device__ __forceinline__ float relu_f(float x) { return fmaxf(x, 0.f); }

__device__ __forceinline__ unsigned short f2bf(float x) {
    union { float f; unsigned int u; } v; v.f = x;
    unsigned int r = v.u + 0x7fffu + ((v.u >> 16) & 1u);   // RNE
    return (unsigned short)(r >> 16);
}

__device__ __forceinline__ float bflo(unsigned int u) {
    union { unsigned int x; float f; } v; v.x = u << 16; return v.f;
}

__device__ __forceinline__ void gload_lds16(const void* g, void* l) {
    __builtin_amdgcn_global_load_lds(
        (const __attribute__((address_space(1))) void*)g,
        (__attribute__((address_space(3))) void*)l, 16, 0, 0);
}

// ---------------- prep: convert_fv + 3 weight transposes + box features ----------------
__device__ __forceinline__ void transpose_tile(
    const float* __restrict__ W, unsigned short* __restrict__ Wt,
    int Ncols, int k0, int o0, float (*ld)[65])
{
    const int t = threadIdx.x;
    const int r = t >> 2;
    const int c0 = (t & 3) * 16;
    #pragma unroll
    for (int i = 0; i < 4; ++i) {
        float4 v = *reinterpret_cast<const float4*>(&W[(size_t)(k0 + r) * Ncols + o0 + c0 + i * 4]);
        ld[c0 + i * 4 + 0][r] = v.x;
        ld[c0 + i * 4 + 1][r] = v.y;
        ld[c0 + i * 4 + 2][r] = v.z;
        ld[c0 + i * 4 + 3][r] = v.w;
    }
    __syncthreads();
    const int o = t >> 2;
    const int kc = (t & 3) * 16;
    unsigned int u[8];
    #pragma unroll
    for (int j = 0; j < 8; ++j) {
        float x0 = ld[o][kc + 2 * j], x1 = ld[o][kc + 2 * j + 1];
        u[j] = (unsigned)f2bf(x0) | ((unsigned)f2bf(x1) << 16);
    }
    uint4* dst = reinterpret_cast<uint4*>(&Wt[(size_t)(o0 + o) * DV + k0 + kc]);
    dst[0] = make_uint4(u[0], u[1], u[2], u[3]);
    dst[1] = make_uint4(u[4], u[5], u[6], u[7]);
}

__global__ __launch_bounds__(256) void prep_kernel(
    const float* __restrict__ feat,
    const float* __restrict__ Wk, const float* __restrict__ Wq, const float* __restrict__ Wv,
    const float* __restrict__ rois,
    unsigned short* __restrict__ fvb, unsigned short* __restrict__ WkqT,
    unsigned short* __restrict__ WvT,
    float4* __restrict__ boxf, float2* __restrict__ boxinv)
{
    __shared__ float ld[64][65];
    const int bid = blockIdx.x;
    if (bid < 1024) {
        const int idx = bid * 256 + threadIdx.x;
        const float4 a = *reinterpret_cast<const float4*>(feat + (size_t)idx * 8);
        const float4 b = *reinterpret_cast<const float4*>(feat + (size_t)idx * 8 + 4);
        uint4 o;
        o.x = (unsigned)f2bf(relu_f(a.x)) | ((unsigned)f2bf(relu_f(a.y)) << 16);
        o.y = (unsigned)f2bf(relu_f(a.z)) | ((unsigned)f2bf(relu_f(a.w)) << 16);
        o.z = (unsigned)f2bf(relu_f(b.x)) | ((unsigned)f2bf(relu_f(b.y)) << 16);
        o.w = (unsigned)f2bf(relu_f(b.z)) | ((unsigned)f2bf(relu_f(b.w)) << 16);
        *reinterpret_cast<uint4*>(fvb + (size_t)idx * 8) = o;
    } else if (bid < 2048) {
        const int idx = bid - 1024;                 // 32x32 tiles of Wv
        transpose_tile(Wv, WvT, DO, (idx >> 5) * 64, (idx & 31) * 64, ld);
    } else if (bid < 2080) {
        transpose_tile(Wk, WkqT, DMM, (bid - 2048) * 64, 0, ld);
    } else if (bid < 2112) {
        transpose_tile(Wq, WkqT + 64 * DV, DMM, (bid - 2080) * 64, 0, ld);
    } else {
        const int idx = (bid - 2112) * 256 + threadIdx.x;   // 0..1023
        const float4 r = *reinterpret_cast<const float4*>(rois + (size_t)idx * 4);
        const float w = r.z - r.x, h = r.w - r.y;
        boxf[idx]   = make_float4(0.5f * (r.x + r.z), 0.5f * (r.y + r.w), __logf(w), __logf(h));
        boxinv[idx] = make_float2(1.f / w, 1.f / h);
    }
}

// ---- 64xBN MFMA tile core, BK=64, 2-buffer counted-vmcnt, XOR-swizzled LDS ----
// EXACT R9 schedule (64.8us local optimum). BNR = BN/32 (4 -> BN=128, 2 -> BN=64).
// SUMA: accumulate fp32 sums of A-fragment rows into rs[2] (wc==0 waves only) --
// used by gemm_out to recover attention row-sums for free.
// Swizzle (rule #21): slot (row r, c') holds global chunk c'^(r&7); stage lane l
// covers row (g*8 + l>>3) chunk (l&7)^(l>>3) -> 128B-coalesced; read chunk
// fq^(fr&7) -> conflict-free. vmcnt(6) in loop; vmcnt(0) only in epilogue.
// Do NOT: split the MFMA cluster, setprio, 3-buffer, XCD-swizzle (R10-R13 regressions).
template<int NT, int LDA, int LDB, int BNR, bool SUMA>
__device__ __forceinline__ void mfma_tile_pipe(
    const unsigned short* __restrict__ A, const unsigned short* __restrict__ Bt,
    int bm0, int bn0, unsigned short* As, unsigned short* Bs,
    f32x4 (&acc)[2][BNR], float* rs)
{
    const int t = threadIdx.x;
    const int w = t >> 6, lane = t & 63;
    const int wr = w >> 1, wc = w & 1;
    const int fr = lane & 15, fq = lane >> 4;
    const int sr = lane >> 3;                 // staged row within 8-row group
    const int sc = ((lane & 7) ^ sr) * 8;     // swizzled chunk offset (elements)

    const unsigned short* ga0 = A + (size_t)(bm0 + w * 16 + 0 + sr) * LDA + sc;
    const unsigned short* ga1 = A + (size_t)(bm0 + w * 16 + 8 + sr) * LDA + sc;
    const unsigned short* gb[BNR];
    #pragma unroll
    for (int g = 0; g < BNR; ++g)
        gb[g] = Bt + (size_t)(bn0 + w * (BNR * 8) + g * 8 + sr) * LDB + sc;

#define STAGE(buf, ts_) do {                                                   \
        const size_t ko_ = (size_t)(ts_) * 64;                                 \
        gload_lds16(ga0 + ko_, &As[(buf) * 4096 + w * 1024]);                  \
        gload_lds16(ga1 + ko_, &As[(buf) * 4096 + w * 1024 + 512]);            \
        _Pragma("unroll")                                                      \
        for (int g = 0; g < BNR; ++g)                                          \
            gload_lds16(gb[g] + ko_,                                           \
                &Bs[(buf) * (BNR * 2048) + w * (BNR * 512) + g * 512]);        \
    } while (0)

#define COMPUTE(buf) do {                                                                     \
        const int kx_ = fr & 7;                                                               \
        const int clo_ = (fq ^ kx_) * 8, chi_ = ((fq + 4) ^ kx_) * 8;                         \
        bf16x8 afl[2], afh[2], bfl[BNR], bfh[BNR];                                            \
        _Pragma("unroll")                                                                     \
        for (int m = 0; m < 2; ++m) {                                                         \
            const int rb = (buf) * 4096 + (wr * 32 + m * 16 + fr) * 64;                       \
            afl[m] = *reinterpret_cast<const bf16x8*>(&As[rb + clo_]);                        \
            afh[m] = *reinterpret_cast<const bf16x8*>(&As[rb + chi_]);                        \
        }                                                                                     \
        _Pragma("unroll")                                                                     \
        for (int n = 0; n < BNR; ++n) {                                                       \
            const int cb = (buf) * (BNR * 2048) + (wc * (BNR * 16) + n * 16 + fr) * 64;       \
            bfl[n] = *reinterpret_cast<const bf16x8*>(&Bs[cb + clo_]);                        \
            bfh[n] = *reinterpret_cast<const bf16x8*>(&Bs[cb + chi_]);                        \
        }                                                                                     \
        if (SUMA && wc == 0) {                                                                \
            _Pragma("unroll")                                                                 \
            for (int m = 0; m < 2; ++m) {                                                     \
                u16x8 sl = __builtin_bit_cast(u16x8, afl[m]);                                 \
                u16x8 sh = __builtin_bit_cast(u16x8, afh[m]);                                 \
                _Pragma("unroll")                                                             \
                for (int e = 0; e < 8; ++e)                                                   \
                    rs[m] += bflo(sl[e]) + bflo(sh[e]);                                       \
            }                                                                                 \
        }                                                                                     \
        _Pragma("unroll")                                                                     \
        for (int m = 0; m < 2; ++m)                                                           \
            _Pragma("unroll")                                                                 \
            for (int n = 0; n < BNR; ++n) {                                                   \
                acc[m][n] = __builtin_amdgcn_mfma_f32_16x16x32_bf16(afl[m], bfl[n], acc[m][n], 0, 0, 0); \
                acc[m][n] = __builtin_amdgcn_mfma_f32_16x16x32_bf16(afh[m], bfh[n], acc[m][n], 0, 0, 0); \
            }                                                                                 \
    } while (0)

    STAGE(0, 0);
    if (NT > 1) STAGE(1, 1);

    #pragma unroll 2
    for (int ts = 0; ts < NT - 1; ++ts) {
        if (BNR == 4) { asm volatile("s_waitcnt vmcnt(6)" ::: "memory"); }
        else          { asm volatile("s_waitcnt vmcnt(4)" ::: "memory"); }
        asm volatile("s_barrier" ::: "memory");            // all waves' stage ts done
        COMPUTE(ts & 1);
        asm volatile("s_barrier" ::: "memory");            // all waves done reading buf
        if (ts + 2 < NT) STAGE(ts & 1, ts + 2);
    }
    asm volatile("s_waitcnt vmcnt(0)" ::: "memory");
    asm volatile("s_barrier" ::: "memory");
    COMPUTE((NT - 1) & 1);
#undef STAGE
#undef COMPUTE
}

// ---------------- fused vT GEMM (256 blocks) + kq GEMM (16 blocks) ----------------
__global__ __launch_bounds__(256) void gemm_vt_kq(
    const unsigned short* __restrict__ WvT, const unsigned short* __restrict__ fvb,
    const unsigned short* __restrict__ WkqT,
    const float* __restrict__ bv, const float* __restrict__ bk, const float* __restrict__ bq,
    unsigned short* __restrict__ vT, unsigned short* __restrict__ kqb)
{
    __shared__ unsigned short As[2 * 64 * 64];    // 16 KB
    __shared__ unsigned short Bs[2 * 128 * 64];   // 32 KB
    const int bid = blockIdx.x;
    const bool is_kq = bid >= 256;
    const unsigned short* A  = is_kq ? fvb  : WvT;
    const unsigned short* Bt = is_kq ? WkqT : fvb;
    const int bm0 = is_kq ? (bid - 256) * 64 : (bid >> 3) * 64;
    const int bn0 = is_kq ? 0 : (bid & 7) * 128;

    f32x4 acc[2][4] = {};
    mfma_tile_pipe<DV / 64, DV, DV, 4, false>(A, Bt, bm0, bn0, As, Bs, acc, nullptr);

    const int t = threadIdx.x;
    const int w = t >> 6, lane = t & 63;
    const int wr = w >> 1, wc = w & 1;
    const int fr = lane & 15, fq = lane >> 4;
    if (!is_kq) {
        #pragma unroll
        for (int m = 0; m < 2; ++m)
            #pragma unroll
            for (int r = 0; r < 4; ++r) {
                const int row = bm0 + wr * 32 + m * 16 + fq * 4 + r;
                const float badd = bv[row];
                #pragma unroll
                for (int n = 0; n < 4; ++n) {
                    const int col = bn0 + wc * 64 + n * 16 + fr;
                    vT[(size_t)row * NR + col] = f2bf(acc[m][n][r] + badd);
                }
            }
    } else {
        #pragma unroll
        for (int m = 0; m < 2; ++m)
            #pragma unroll
            for (int r = 0; r < 4; ++r) {
                const int row = bm0 + wr * 32 + m * 16 + fq * 4 + r;
                #pragma unroll
                for (int n = 0; n < 4; ++n) {
                    const int col = wc * 64 + n * 16 + fr;
                    const float badd = (col < 64) ? bk[col] : bq[col - 64];
                    kqb[(size_t)row * 128 + col] = f2bf(acc[m][n][r] + badd);
                }
            }
    }
}

// ---------------- s_geo: att~[i][j] = exp(<k_i,q_j>/8) * geoMLP(i,j), diag=0 ----------------
// 64x64 S-tiles, 256 blocks (full chip). Unnormalized bf16 out; normalization
// happens in gemm_out via row sums recovered from its A fragments.
#define MLP_STEP8(A_, B_, C_, D_, E_, F_)                                           \
    {                                                                               \
        _Pragma("unroll")                                                           \
        for (int p = 0; p < 8; ++p) {                                               \
            float h_ = fmaf(ff1[p], A_, fmaf(ff2[p], B_, fmaf(ff3[p], C_,           \
                       fmaf(ff4[p], D_, E_))));                                     \
            h_ = fmaxf(h_, 0.f);                                                    \
            gw[p] = fmaf(h_, F_, gw[p]);                                            \
        }                                                                           \
    }

__global__ __launch_bounds__(256) void s_geo(
    const unsigned short* __restrict__ kqb,
    const float4* __restrict__ boxf, const float2* __restrict__ boxinv,
    const float* __restrict__ G1, const float* __restrict__ g1,
    const float* __restrict__ G2, const float* __restrict__ g2,
    unsigned short* __restrict__ att)
{
    __shared__ unsigned short As[64 * 64];    // NT=1: single buffer
    __shared__ unsigned short Bs[64 * 64];
    __shared__ float G1s[4][64];
    __shared__ float g1s[64];
    __shared__ float G2s[64];
    const int t = threadIdx.x;
    if (t < 64) {
        G1s[0][t] = G1[t];
        G1s[1][t] = G1[64 + t];
        G1s[2][t] = G1[128 + t];
        G1s[3][t] = G1[192 + t];
        g1s[t] = g1[t];
        G2s[t] = G2[t];
    }
    __syncthreads();   // weights visible (full lgkm drain) before epilogue use

    const int bm0 = blockIdx.y * 64;
    const int bn0 = blockIdx.x * 64;
    f32x4 acc[2][2] = {};
    mfma_tile_pipe<1, 128, 128, 2, false>(kqb, kqb + 64, bm0, bn0, As, Bs, acc, nullptr);

    const int w = t >> 6, lane = t & 63;
    const int wr = w >> 1, wc = w & 1;
    const int fr = lane & 15, fq = lane >> 4;
    const float g2v = g2[0];

    #pragma unroll
    for (int m = 0; m < 2; ++m) {
        const int rbase = bm0 + wr * 32 + m * 16 + fq * 4;
        float ff1[8], ff2[8], ff3[8], ff4[8], sv[8], gw[8];
        #pragma unroll
        for (int n = 0; n < 2; ++n) {
            const int col = bn0 + wc * 32 + n * 16 + fr;
            const float4 bj = boxf[col];
            #pragma unroll
            for (int r = 0; r < 4; ++r) {
                const int row = rbase + r;
                const float4 bi = boxf[row];
                const float2 ivi = boxinv[row];
                const int p = n * 4 + r;
                sv[p] = acc[m][n][r] * 0.125f;
                ff1[p] = __logf(fmaf(fabsf(bj.x - bi.x), ivi.x, 1e-3f));
                ff2[p] = __logf(fmaf(fabsf(bj.y - bi.y), ivi.y, 1e-3f));
                ff3[p] = bj.z - bi.z;
                ff4[p] = bj.w - bi.w;
                gw[p] = 0.f;
            }
        }
        for (int mt = 0; mt < 64; mt += 8) {
            const float4 A0 = *reinterpret_cast<const float4*>(&G1s[0][mt]);
            const float4 A1 = *reinterpret_cast<const float4*>(&G1s[0][mt + 4]);
            const float4 B0 = *reinterpret_cast<const float4*>(&G1s[1][mt]);
            const float4 B1 = *reinterpret_cast<const float4*>(&G1s[1][mt + 4]);
            const float4 C0 = *reinterpret_cast<const float4*>(&G1s[2][mt]);
            const float4 C1 = *reinterpret_cast<const float4*>(&G1s[2][mt + 4]);
            const float4 D0 = *reinterpret_cast<const float4*>(&G1s[3][mt]);
            const float4 D1 = *reinterpret_cast<const float4*>(&G1s[3][mt + 4]);
            const float4 E0 = *reinterpret_cast<const float4*>(&g1s[mt]);
            const float4 E1 = *reinterpret_cast<const float4*>(&g1s[mt + 4]);
            const float4 F0 = *reinterpret_cast<const float4*>(&G2s[mt]);
            const float4 F1 = *reinterpret_cast<const float4*>(&G2s[mt + 4]);
            MLP_STEP8(A0.x, B0.x, C0.x, D0.x, E0.x, F0.x)
            MLP_STEP8(A0.y, B0.y, C0.y, D0.y, E0.y, F0.y)
            MLP_STEP8(A0.z, B0.z, C0.z, D0.z, E0.z, F0.z)
            MLP_STEP8(A0.w, B0.w, C0.w, D0.w, E0.w, F0.w)
            MLP_STEP8(A1.x, B1.x, C1.x, D1.x, E1.x, F1.x)
            MLP_STEP8(A1.y, B1.y, C1.y, D1.y, E1.y, F1.y)
            MLP_STEP8(A1.z, B1.z, C1.z, D1.z, E1.z, F1.z)
            MLP_STEP8(A1.w, B1.w, C1.w, D1.w, E1.w, F1.w)
        }
        #pragma unroll
        for (int n = 0; n < 2; ++n) {
            const int col = bn0 + wc * 32 + n * 16 + fr;
            #pragma unroll
            for (int r = 0; r < 4; ++r) {
                const int row = rbase + r;
                const int p = n * 4 + r;
                float a = __expf(sv[p]) * fmaxf(gw[p] + g2v, 0.f);
                if (row == col) a = 0.f;
                att[(size_t)row * NR + col] = f2bf(a);
            }
        }
    }
}

// ---------------- out GEMM with fused normalization (256 blocks) ----------------
// out[i][:] = (att~[i][:] @ vT^T) / (rowsum_i + 1e-10); rowsum recovered from
// the A fragments already loaded for MFMA (wc==0 waves, fp32 accumulate).
__global__ __launch_bounds__(256) void gemm_out(
    const unsigned short* __restrict__ attb, const unsigned short* __restrict__ vT,
    float* __restrict__ out)
{
    __shared__ unsigned short As[2 * 64 * 64];
    __shared__ unsigned short Bs[2 * 128 * 64];
    __shared__ float sinv[64];
    const int bm0 = blockIdx.y * 64;
    const int bn0 = blockIdx.x * 128;
    f32x4 acc[2][4] = {};
    float rs[2] = {0.f, 0.f};
    mfma_tile_pipe<NR / 64, NR, NR, 4, true>(attb, vT, bm0, bn0, As, Bs, acc, rs);

    const int t = threadIdx.x;
    const int w = t >> 6, lane = t & 63;
    const int wr = w >> 1, wc = w & 1;
    const int fr = lane & 15, fq = lane >> 4;

    if (wc == 0) {
        #pragma unroll
        for (int m = 0; m < 2; ++m) {
            float v = rs[m];
            v += __shfl_xor(v, 16, 64);    // reduce over fq bit 0
            v += __shfl_xor(v, 32, 64);    // reduce over fq bit 1
            if (fq == 0) sinv[wr * 32 + m * 16 + fr] = 1.0f / (v + 1e-10f);
        }
    }
    __syncthreads();

    #pragma unroll
    for (int m = 0; m < 2; ++m)
        #pragma unroll
        for (int r = 0; r < 4; ++r) {
            const int rl = wr * 32 + m * 16 + fq * 4 + r;
            const int row = bm0 + rl;
            const float sc_ = sinv[rl];
            #pragma unroll
            for (int n = 0; n < 4; ++n) {
                const int col = bn0 + wc * 64 + n * 16 + fr;
                out[(size_t)row * DO + col] = acc[m][n][r] * sc_;
            }
        }
}

extern "C" void kernel_launch(void* const* d_in, const int* in_sizes, int n_in,
                              void* d_out, int out_size, void* d_ws, size_t ws_size,
                              hipStream_t stream) {
    const float* feat = (const float*)d_in[0];
    const float* rois = (const float*)d_in[1];
    const float* Wk   = (const float*)d_in[2];
    const float* bk   = (const float*)d_in[3];
    const float* Wq   = (const float*)d_in[4];
    const float* bq   = (const float*)d_in[5];
    const float* Wv   = (const float*)d_in[6];
    const float* bv   = (const float*)d_in[7];
    const float* G1   = (const float*)d_in[8];
    const float* g1   = (const float*)d_in[9];
    const float* G2   = (const float*)d_in[10];
    const float* g2   = (const float*)d_in[11];
    float* out = (float*)d_out;
    char* ws = (char*)d_ws;

    unsigned short* kqb  = (unsigned short*)ws;                                  // 256 KB
    float4* boxf         = (float4*)(ws + (256 << 10));                          // 16 KB
    float2* boxinv       = (float2*)(ws + (272 << 10));                          // 8 KB
    unsigned short* fvb  = (unsigned short*)(ws + (512 << 10));                  // 4 MB
    unsigned short* WvT  = (unsigned short*)(ws + (512 << 10) + (4 << 20));      // 8 MB
    unsigned short* WkqT = (unsigned short*)(ws + (512 << 10) + (12 << 20));     // 512 KB
    unsigned short* vT   = (unsigned short*)(ws + (1024 << 10) + (12 << 20));    // 4 MB
    unsigned short* attb = (unsigned short*)(ws + (1024 << 10) + (16 << 20));    // 2 MB

    prep_kernel<<<2116, 256, 0, stream>>>(feat, Wk, Wq, Wv, rois, fvb, WkqT, WvT, boxf, boxinv);
    gemm_vt_kq<<<272, 256, 0, stream>>>(WvT, fvb, WkqT, bv, bk, bq, vT, kqb);
    s_geo<<<dim3(16, 16), 256, 0, stream>>>(kqb, boxf, boxinv, G1, g1, G2, g2, attb);
    gemm_out<<<dim3(DO / 128, NR / 64), 256, 0, stream>>>(attb, vT, out);
}

// Round 15
// 57.622 us; speedup vs baseline: 1.4689x; 1.1839x over previous
//
#include <hip/hip_runtime.h>
#include <hip/hip_bf16.h>

#define NR 1024
#define DV 2048
#define DMM 64
#define DO 2048

typedef __attribute__((ext_vector_type(8))) __bf16 bf16x8;
typedef __attribute__((ext_vector_type(4))) float f32x4;

__device__ __forceinline__ float relu_f(float x) { return fmaxf(x, 0.f); }

__device__ __forceinline__ unsigned short f2bf(float x) {
    union { float f; unsigned int u; } v; v.f = x;
    unsigned int r = v.u + 0x7fffu + ((v.u >> 16) & 1u);   // RNE
    return (unsigned short)(r >> 16);
}

__device__ __forceinline__ void gload_lds16(const void* g, void* l) {
    __builtin_amdgcn_global_load_lds(
        (const __attribute__((address_space(1))) void*)g,
        (__attribute__((address_space(3))) void*)l, 16, 0, 0);
}

// ---------------- prep: convert_fv + 3 weight transposes + box features ----------------
__device__ __forceinline__ void transpose_tile(
    const float* __restrict__ W, unsigned short* __restrict__ Wt,
    int Ncols, int k0, int o0, float (*ld)[65])
{
    const int t = threadIdx.x;
    const int r = t >> 2;
    const int c0 = (t & 3) * 16;
    #pragma unroll
    for (int i = 0; i < 4; ++i) {
        float4 v = *reinterpret_cast<const float4*>(&W[(size_t)(k0 + r) * Ncols + o0 + c0 + i * 4]);
        ld[c0 + i * 4 + 0][r] = v.x;
        ld[c0 + i * 4 + 1][r] = v.y;
        ld[c0 + i * 4 + 2][r] = v.z;
        ld[c0 + i * 4 + 3][r] = v.w;
    }
    __syncthreads();
    const int o = t >> 2;
    const int kc = (t & 3) * 16;
    unsigned int u[8];
    #pragma unroll
    for (int j = 0; j < 8; ++j) {
        float x0 = ld[o][kc + 2 * j], x1 = ld[o][kc + 2 * j + 1];
        u[j] = (unsigned)f2bf(x0) | ((unsigned)f2bf(x1) << 16);
    }
    uint4* dst = reinterpret_cast<uint4*>(&Wt[(size_t)(o0 + o) * DV + k0 + kc]);
    dst[0] = make_uint4(u[0], u[1], u[2], u[3]);
    dst[1] = make_uint4(u[4], u[5], u[6], u[7]);
}

__global__ __launch_bounds__(256) void prep_kernel(
    const float* __restrict__ feat,
    const float* __restrict__ Wk, const float* __restrict__ Wq, const float* __restrict__ Wv,
    const float* __restrict__ rois,
    unsigned short* __restrict__ fvb, unsigned short* __restrict__ WkqT,
    unsigned short* __restrict__ WvT,
    float4* __restrict__ boxf, float2* __restrict__ boxinv)
{
    __shared__ float ld[64][65];
    const int bid = blockIdx.x;
    if (bid < 1024) {
        const int idx = bid * 256 + threadIdx.x;
        const float4 a = *reinterpret_cast<const float4*>(feat + (size_t)idx * 8);
        const float4 b = *reinterpret_cast<const float4*>(feat + (size_t)idx * 8 + 4);
        uint4 o;
        o.x = (unsigned)f2bf(relu_f(a.x)) | ((unsigned)f2bf(relu_f(a.y)) << 16);
        o.y = (unsigned)f2bf(relu_f(a.z)) | ((unsigned)f2bf(relu_f(a.w)) << 16);
        o.z = (unsigned)f2bf(relu_f(b.x)) | ((unsigned)f2bf(relu_f(b.y)) << 16);
        o.w = (unsigned)f2bf(relu_f(b.z)) | ((unsigned)f2bf(relu_f(b.w)) << 16);
        *reinterpret_cast<uint4*>(fvb + (size_t)idx * 8) = o;
    } else if (bid < 2048) {
        const int idx = bid - 1024;                 // 32x32 tiles of Wv
        transpose_tile(Wv, WvT, DO, (idx >> 5) * 64, (idx & 31) * 64, ld);
    } else if (bid < 2080) {
        transpose_tile(Wk, WkqT, DMM, (bid - 2048) * 64, 0, ld);
    } else if (bid < 2112) {
        transpose_tile(Wq, WkqT + 64 * DV, DMM, (bid - 2080) * 64, 0, ld);
    } else {
        const int idx = (bid - 2112) * 256 + threadIdx.x;   // 0..1023
        const float4 r = *reinterpret_cast<const float4*>(rois + (size_t)idx * 4);
        const float w = r.z - r.x, h = r.w - r.y;
        boxf[idx]   = make_float4(0.5f * (r.x + r.z), 0.5f * (r.y + r.w), __logf(w), __logf(h));
        boxinv[idx] = make_float2(1.f / w, 1.f / h);
    }
}

// ---- 64x(BNR*32) MFMA tile core, BK=64, 2-buffer counted-vmcnt, XOR-swizzled LDS ----
// R9 schedule (proven local optimum). BNR=4 -> BN=128 (R9 exact); BNR=2 -> BN=64,
// which doubles the grid for TLP: 2 blocks/CU overlap each other's barrier drains
// (m114 mechanism) -- the thing no in-block pipeline variant (R6-R13) could create.
// Swizzle (rule #21): slot (row r, c') holds global chunk c'^(r&7); stage lane l
// covers row (g*8 + l>>3) chunk (l&7)^(l>>3) -> 128B-coalesced; read chunk
// fq^(fr&7) -> conflict-free. vmcnt(2+BNR) in loop; vmcnt(0) only in epilogue.
// Do NOT: split the MFMA cluster, setprio, 3-buffer, XCD-swizzle (R10-R13 regressions).
template<int NT, int LDA, int LDB, int BNR>
__device__ __forceinline__ void mfma_tile_pipe(
    const unsigned short* __restrict__ A, const unsigned short* __restrict__ Bt,
    int bm0, int bn0, unsigned short* As, unsigned short* Bs, f32x4 (&acc)[2][BNR])
{
    const int t = threadIdx.x;
    const int w = t >> 6, lane = t & 63;
    const int wr = w >> 1, wc = w & 1;
    const int fr = lane & 15, fq = lane >> 4;
    const int sr = lane >> 3;                 // staged row within 8-row group
    const int sc = ((lane & 7) ^ sr) * 8;     // swizzled chunk offset (elements)

    const unsigned short* ga0 = A + (size_t)(bm0 + w * 16 + 0 + sr) * LDA + sc;
    const unsigned short* ga1 = A + (size_t)(bm0 + w * 16 + 8 + sr) * LDA + sc;
    const unsigned short* gb[BNR];
    #pragma unroll
    for (int g = 0; g < BNR; ++g)
        gb[g] = Bt + (size_t)(bn0 + w * (BNR * 8) + g * 8 + sr) * LDB + sc;

#define STAGE(buf, ts_) do {                                                   \
        const size_t ko_ = (size_t)(ts_) * 64;                                 \
        gload_lds16(ga0 + ko_, &As[(buf) * 4096 + w * 1024]);                  \
        gload_lds16(ga1 + ko_, &As[(buf) * 4096 + w * 1024 + 512]);            \
        _Pragma("unroll")                                                      \
        for (int g = 0; g < BNR; ++g)                                          \
            gload_lds16(gb[g] + ko_,                                           \
                &Bs[(buf) * (BNR * 2048) + w * (BNR * 512) + g * 512]);        \
    } while (0)

#define COMPUTE(buf) do {                                                                     \
        const int kx_ = fr & 7;                                                               \
        const int clo_ = (fq ^ kx_) * 8, chi_ = ((fq + 4) ^ kx_) * 8;                         \
        bf16x8 afl[2], afh[2], bfl[BNR], bfh[BNR];                                            \
        _Pragma("unroll")                                                                     \
        for (int m = 0; m < 2; ++m) {                                                         \
            const int rb = (buf) * 4096 + (wr * 32 + m * 16 + fr) * 64;                       \
            afl[m] = *reinterpret_cast<const bf16x8*>(&As[rb + clo_]);                        \
            afh[m] = *reinterpret_cast<const bf16x8*>(&As[rb + chi_]);                        \
        }                                                                                     \
        _Pragma("unroll")                                                                     \
        for (int n = 0; n < BNR; ++n) {                                                       \
            const int cb = (buf) * (BNR * 2048) + (wc * (BNR * 16) + n * 16 + fr) * 64;       \
            bfl[n] = *reinterpret_cast<const bf16x8*>(&Bs[cb + clo_]);                        \
            bfh[n] = *reinterpret_cast<const bf16x8*>(&Bs[cb + chi_]);                        \
        }                                                                                     \
        _Pragma("unroll")                                                                     \
        for (int m = 0; m < 2; ++m)                                                           \
            _Pragma("unroll")                                                                 \
            for (int n = 0; n < BNR; ++n) {                                                   \
                acc[m][n] = __builtin_amdgcn_mfma_f32_16x16x32_bf16(afl[m], bfl[n], acc[m][n], 0, 0, 0); \
                acc[m][n] = __builtin_amdgcn_mfma_f32_16x16x32_bf16(afh[m], bfh[n], acc[m][n], 0, 0, 0); \
            }                                                                                 \
    } while (0)

    STAGE(0, 0);
    if (NT > 1) STAGE(1, 1);

    #pragma unroll 2
    for (int ts = 0; ts < NT - 1; ++ts) {
        if (BNR == 4) { asm volatile("s_waitcnt vmcnt(6)" ::: "memory"); }
        else          { asm volatile("s_waitcnt vmcnt(4)" ::: "memory"); }
        asm volatile("s_barrier" ::: "memory");            // all waves' stage ts done
        COMPUTE(ts & 1);
        asm volatile("s_barrier" ::: "memory");            // all waves done reading buf
        if (ts + 2 < NT) STAGE(ts & 1, ts + 2);
    }
    asm volatile("s_waitcnt vmcnt(0)" ::: "memory");
    asm volatile("s_barrier" ::: "memory");
    COMPUTE((NT - 1) & 1);
#undef STAGE
#undef COMPUTE
}

// ---------------- fused vT GEMM (512 blocks, 64x64) + kq GEMM (32 blocks) ----------------
// vT[DO][NR] = WvT[DO][DV] @ fvb[NR][DV]^T + bv[row]          (bf16 out)
// kqb[NR][128] = fvb[NR][DV] @ WkqT[128][DV]^T + {bk|bq}[col]  (bf16 out)
// bn inner (bid&15) so the default bid->XCD round-robin keeps B panels L2-local.
__global__ __launch_bounds__(256) void gemm_vt_kq(
    const unsigned short* __restrict__ WvT, const unsigned short* __restrict__ fvb,
    const unsigned short* __restrict__ WkqT,
    const float* __restrict__ bv, const float* __restrict__ bk, const float* __restrict__ bq,
    unsigned short* __restrict__ vT, unsigned short* __restrict__ kqb)
{
    __shared__ unsigned short As[2 * 64 * 64];    // 16 KB
    __shared__ unsigned short Bs[2 * 64 * 64];    // 16 KB
    const int bid = blockIdx.x;
    const bool is_kq = bid >= 512;
    const unsigned short* A  = is_kq ? fvb  : WvT;
    const unsigned short* Bt = is_kq ? WkqT : fvb;
    const int bm0 = is_kq ? ((bid - 512) >> 1) * 64 : (bid >> 4) * 64;
    const int bn0 = is_kq ? ((bid - 512) & 1) * 64 : (bid & 15) * 64;

    f32x4 acc[2][2] = {};
    mfma_tile_pipe<DV / 64, DV, DV, 2>(A, Bt, bm0, bn0, As, Bs, acc);

    const int t = threadIdx.x;
    const int w = t >> 6, lane = t & 63;
    const int wr = w >> 1, wc = w & 1;
    const int fr = lane & 15, fq = lane >> 4;
    if (!is_kq) {
        #pragma unroll
        for (int m = 0; m < 2; ++m)
            #pragma unroll
            for (int r = 0; r < 4; ++r) {
                const int row = bm0 + wr * 32 + m * 16 + fq * 4 + r;
                const float badd = bv[row];
                #pragma unroll
                for (int n = 0; n < 2; ++n) {
                    const int col = bn0 + wc * 32 + n * 16 + fr;
                    vT[(size_t)row * NR + col] = f2bf(acc[m][n][r] + badd);
                }
            }
    } else {
        #pragma unroll
        for (int m = 0; m < 2; ++m)
            #pragma unroll
            for (int r = 0; r < 4; ++r) {
                const int row = bm0 + wr * 32 + m * 16 + fq * 4 + r;
                #pragma unroll
                for (int n = 0; n < 2; ++n) {
                    const int col = bn0 + wc * 32 + n * 16 + fr;
                    const float badd = (col < 64) ? bk[col] : bq[col - 64];
                    kqb[(size_t)row * 128 + col] = f2bf(acc[m][n][r] + badd);
                }
            }
    }
}

// ---------------- S[i][j] = 0.125 * <k_i, q_j>  (K=64 MFMA GEMM, 128 blocks, R9) ----------------
__global__ __launch_bounds__(256) void gemm_s(
    const unsigned short* __restrict__ kqb, float* __restrict__ S)
{
    __shared__ unsigned short As[64 * 64];     // NT=1: only buffer 0 used
    __shared__ unsigned short Bs[128 * 64];
    const int bm0 = blockIdx.y * 64;
    const int bn0 = blockIdx.x * 128;
    f32x4 acc[2][4] = {};
    mfma_tile_pipe<1, 128, 128, 4>(kqb, kqb + 64, bm0, bn0, As, Bs, acc);
    const int t = threadIdx.x;
    const int w = t >> 6, lane = t & 63;
    const int wr = w >> 1, wc = w & 1;
    const int fr = lane & 15, fq = lane >> 4;
    #pragma unroll
    for (int m = 0; m < 2; ++m)
        #pragma unroll
        for (int r = 0; r < 4; ++r) {
            const int row = bm0 + wr * 32 + m * 16 + fq * 4 + r;
            #pragma unroll
            for (int n = 0; n < 4; ++n) {
                const int col = bn0 + wc * 64 + n * 16 + fr;
                S[(size_t)row * NR + col] = acc[m][n][r] * 0.125f;
            }
        }
}

// ---------------- out GEMM: out[NR][DO] = attb @ vT^T  (512 blocks, 64x64) ----------------
__global__ __launch_bounds__(256) void gemm_out(
    const unsigned short* __restrict__ attb, const unsigned short* __restrict__ vT,
    float* __restrict__ out)
{
    __shared__ unsigned short As[2 * 64 * 64];
    __shared__ unsigned short Bs[2 * 64 * 64];
    const int bid = blockIdx.x;
    const int bm0 = (bid >> 5) * 64;    // 16 bm panels
    const int bn0 = (bid & 31) * 64;    // 32 bn panels (inner -> XCD-local B)
    f32x4 acc[2][2] = {};
    mfma_tile_pipe<NR / 64, NR, NR, 2>(attb, vT, bm0, bn0, As, Bs, acc);
    const int t = threadIdx.x;
    const int w = t >> 6, lane = t & 63;
    const int wr = w >> 1, wc = w & 1;
    const int fr = lane & 15, fq = lane >> 4;
    #pragma unroll
    for (int m = 0; m < 2; ++m)
        #pragma unroll
        for (int r = 0; r < 4; ++r) {
            const int row = bm0 + wr * 32 + m * 16 + fq * 4 + r;
            #pragma unroll
            for (int n = 0; n < 2; ++n) {
                const int col = bn0 + wc * 32 + n * 16 + fr;
                out[(size_t)row * DO + col] = acc[m][n][r];
            }
        }
}

// ---------------- attention row kernel: VALU-only MLP, S precomputed (R9 version) ----------------
#define MLP_STEP(A_, B_, C_, D_, E_, F_)                                            \
    {                                                                               \
        float h_ = fmaf(ff1[ch], A_, fmaf(ff2[ch], B_, fmaf(ff3[ch], C_,            \
                   fmaf(ff4[ch], D_, E_))));                                        \
        h_ = fmaxf(h_, 0.f);                                                        \
        gw[ch] = fmaf(h_, F_, gw[ch]);                                              \
    }

__global__ __launch_bounds__(256) void attn_kernel(
    const float* __restrict__ S,
    const float4* __restrict__ boxf, const float2* __restrict__ boxinv,
    const float* __restrict__ G1, const float* __restrict__ g1,
    const float* __restrict__ G2, const float* __restrict__ g2,
    unsigned short* __restrict__ att)
{
    __shared__ float G1s[4][64];
    __shared__ float g1s[64];
    __shared__ float G2s[64];
    __shared__ float red[4];
    const int i = blockIdx.x;
    const int t = threadIdx.x;
    if (t < 64) {
        G1s[0][t] = G1[t];
        G1s[1][t] = G1[64 + t];
        G1s[2][t] = G1[128 + t];
        G1s[3][t] = G1[192 + t];
        g1s[t] = g1[t];
        G2s[t] = G2[t];
    }
    __syncthreads();
    const float4 bi = boxf[i];
    const float2 ivi = boxinv[i];
    const float g2v = g2[0];

    float ff1[4], ff2[4], ff3[4], ff4[4], sc[4], gw[4] = {0.f, 0.f, 0.f, 0.f};
    #pragma unroll
    for (int ch = 0; ch < 4; ++ch) {
        const int j = ch * 256 + t;
        const float4 bj = boxf[j];
        sc[ch] = S[(size_t)i * NR + j];
        ff1[ch] = __logf(fmaf(fabsf(bj.x - bi.x), ivi.x, 1e-3f));
        ff2[ch] = __logf(fmaf(fabsf(bj.y - bi.y), ivi.y, 1e-3f));
        ff3[ch] = bj.z - bi.z;
        ff4[ch] = bj.w - bi.w;
    }

    for (int mt = 0; mt < 64; mt += 8) {
        const float4 A0 = *reinterpret_cast<const float4*>(&G1s[0][mt]);
        const float4 A1 = *reinterpret_cast<const float4*>(&G1s[0][mt + 4]);
        const float4 B0 = *reinterpret_cast<const float4*>(&G1s[1][mt]);
        const float4 B1 = *reinterpret_cast<const float4*>(&G1s[1][mt + 4]);
        const float4 C0 = *reinterpret_cast<const float4*>(&G1s[2][mt]);
        const float4 C1 = *reinterpret_cast<const float4*>(&G1s[2][mt + 4]);
        const float4 D0 = *reinterpret_cast<const float4*>(&G1s[3][mt]);
        const float4 D1 = *reinterpret_cast<const float4*>(&G1s[3][mt + 4]);
        const float4 E0 = *reinterpret_cast<const float4*>(&g1s[mt]);
        const float4 E1 = *reinterpret_cast<const float4*>(&g1s[mt + 4]);
        const float4 F0 = *reinterpret_cast<const float4*>(&G2s[mt]);
        const float4 F1 = *reinterpret_cast<const float4*>(&G2s[mt + 4]);
        #pragma unroll
        for (int ch = 0; ch < 4; ++ch) {
            MLP_STEP(A0.x, B0.x, C0.x, D0.x, E0.x, F0.x)
            MLP_STEP(A0.y, B0.y, C0.y, D0.y, E0.y, F0.y)
            MLP_STEP(A0.z, B0.z, C0.z, D0.z, E0.z, F0.z)
            MLP_STEP(A0.w, B0.w, C0.w, D0.w, E0.w, F0.w)
            MLP_STEP(A1.x, B1.x, C1.x, D1.x, E1.x, F1.x)
            MLP_STEP(A1.y, B1.y, C1.y, D1.y, E1.y, F1.y)
            MLP_STEP(A1.z, B1.z, C1.z, D1.z, E1.z, F1.z)
            MLP_STEP(A1.w, B1.w, C1.w, D1.w, E1.w, F1.w)
        }
    }

    float vals[4];
    float rsum = 0.f;
    #pragma unroll
    for (int ch = 0; ch < 4; ++ch) {
        const float gwp = fmaxf(gw[ch] + g2v, 0.f);
        float a = __expf(sc[ch]) * gwp;
        if (ch * 256 + t == i) a = 0.f;
        vals[ch] = a;
        rsum += a;
    }
    #pragma unroll
    for (int o = 32; o > 0; o >>= 1) rsum += __shfl_down(rsum, o, 64);
    if ((t & 63) == 0) red[t >> 6] = rsum;
    __syncthreads();
    const float inv = 1.f / (red[0] + red[1] + red[2] + red[3] + 1e-10f);
    #pragma unroll
    for (int ch = 0; ch < 4; ++ch)
        att[(size_t)i * NR + ch * 256 + t] = f2bf(vals[ch] * inv);
}

extern "C" void kernel_launch(void* const* d_in, const int* in_sizes, int n_in,
                              void* d_out, int out_size, void* d_ws, size_t ws_size,
                              hipStream_t stream) {
    const float* feat = (const float*)d_in[0];
    const float* rois = (const float*)d_in[1];
    const float* Wk   = (const float*)d_in[2];
    const float* bk   = (const float*)d_in[3];
    const float* Wq   = (const float*)d_in[4];
    const float* bq   = (const float*)d_in[5];
    const float* Wv   = (const float*)d_in[6];
    const float* bv   = (const float*)d_in[7];
    const float* G1   = (const float*)d_in[8];
    const float* g1   = (const float*)d_in[9];
    const float* G2   = (const float*)d_in[10];
    const float* g2   = (const float*)d_in[11];
    float* out = (float*)d_out;
    char* ws = (char*)d_ws;

    unsigned short* kqb  = (unsigned short*)ws;                                  // 256 KB
    float4* boxf         = (float4*)(ws + (256 << 10));                          // 16 KB
    float2* boxinv       = (float2*)(ws + (272 << 10));                          // 8 KB
    unsigned short* fvb  = (unsigned short*)(ws + (512 << 10));                  // 4 MB
    unsigned short* WvT  = (unsigned short*)(ws + (512 << 10) + (4 << 20));      // 8 MB
    unsigned short* WkqT = (unsigned short*)(ws + (512 << 10) + (12 << 20));     // 512 KB
    unsigned short* vT   = (unsigned short*)(ws + (1024 << 10) + (12 << 20));    // 4 MB
    unsigned short* attb = (unsigned short*)(ws + (1024 << 10) + (16 << 20));    // 2 MB
    float* Sbuf          = (float*)(ws + (1024 << 10) + (18 << 20));             // 4 MB

    prep_kernel<<<2116, 256, 0, stream>>>(feat, Wk, Wq, Wv, rois, fvb, WkqT, WvT, boxf, boxinv);
    gemm_vt_kq<<<544, 256, 0, stream>>>(WvT, fvb, WkqT, bv, bk, bq, vT, kqb);
    gemm_s<<<dim3(8, 16), 256, 0, stream>>>(kqb, Sbuf);
    attn_kernel<<<NR, 256, 0, stream>>>(Sbuf, boxf, boxinv, G1, g1, G2, g2, attb);
    gemm_out<<<512, 256, 0, stream>>>(attb, vT, out);
}